// Round 8
// baseline (89.124 us; speedup 1.0000x reference)
//
#include <hip/hip_runtime.h>

// RenderingModel: scatter-add of 64x64 filters at N particle positions onto a
// 512x512 canvas (cropped). Gather formulation, bf16 col-padded bank (4 MB,
// L2-resident -- R5 proved >4MB thrashes, R6/R7 confirmed FETCH ~17.5MB).
//
// R7 post-mortem: render ~27us, still latency-bound (~9 serialized hit-iters
// per wave, each exposing a full L2 round trip). R8:
//  - 4 hits per loop iteration per wave (k, k+4, k+8, k+12): 16 independent
//    8B loads in flight per thread before the first accumulate drain.
//  - float2 accumulators -> v_pk_add_f32 (8 packed adds/hit vs 16 scalar).
//  - unchanged: wave-split hit list over full 32x32 tile (4x4 px/thread),
//    pure-VALU decode, row guard via offset-cndmask to the part's zero pad,
//    LDS wave-reduce then 4 atomics/thread (1M total), 4 segments.
// Bank: fbank[256][64][128] bf16; filter col j at bank col j+32; rows unpadded.

#define H_  512
#define W_  512
#define FH_ 64
#define FW_ 64
#define NPARTS_ 256
#define BW_ 128
#define TILE_ 32
#define THREADS_ 256
#define SEG_LEN_ 2048

typedef float v2f __attribute__((ext_vector_type(2)));

// 8B of bf16 bank data at only-2B-guaranteed alignment (col parity random).
struct __attribute__((packed, aligned(2))) b8u { unsigned int x, y; };

__device__ __forceinline__ unsigned short f2bf(float f) {
    unsigned u = __float_as_uint(f);
    return (unsigned short)((u + 0x7fffu + ((u >> 16) & 1u)) >> 16);  // RNE
}

__global__ __launch_bounds__(256)
void pad_filters_kernel(const float* __restrict__ filters,
                        unsigned int* __restrict__ bank,   // bf16 pairs
                        float* __restrict__ out) {
    const int part = blockIdx.x;
    const int t    = threadIdx.x;
    unsigned int* dst = bank + part * (FH_ * BW_ / 2);      // 4096 uints/part
    const float* src  = filters + part * (FH_ * FW_);
#pragma unroll
    for (int it = 0; it < 16; ++it) {
        const int u  = t + 256 * it;      // uint slot in [0,4096)
        const int pr = u >> 6;            // bank row 0..63
        const int jp = (u & 63) * 2;      // bank col (even)
        unsigned lo = 0, hi = 0;
        if (jp >= 32 && jp < 96) {        // both cols interior or both pad
            const float* s = src + pr * FW_ + (jp - 32);
            lo = f2bf(s[0]);
            hi = f2bf(s[1]);
        }
        dst[u] = lo | (hi << 16);
    }
    // zero d_out (atomic epilogue needs zeros; harness poisons 0xAA)
    ((float4*)out)[part * 256 + t] = make_float4(0.f, 0.f, 0.f, 0.f);
}

__global__ __launch_bounds__(THREADS_, 4)
void render_tile_kernel(const int* __restrict__ phw,
                        const unsigned short* __restrict__ bank,
                        float* __restrict__ out, int n) {
    __shared__ unsigned int s_list[SEG_LEN_];
    __shared__ float s_red[16 * 4 * 64];   // [slot][wave][lane]
    __shared__ int s_cnt;

    const int t   = threadIdx.x;
    const int tx0 = blockIdx.x * TILE_;
    const int ty0 = blockIdx.y * TILE_;
    const int k0  = blockIdx.z * SEG_LEN_;
    const int k1  = (k0 + SEG_LEN_ < n) ? (k0 + SEG_LEN_) : n;

    if (t == 0) s_cnt = 0;
    __syncthreads();

    // ---- Phase 1: bbox test + compaction of this segment into LDS ----
    for (int k = k0 + t; k < k1; k += THREADS_) {
        const int part = phw[k * 3 + 0];
        const int row  = phw[k * 3 + 1];
        const int col  = phw[k * 3 + 2];
        const bool hit =
            (row >= ty0 - (FH_ / 2 - 1)) && (row <= ty0 + TILE_ - 1 + FH_ / 2) &&
            (col >= tx0 - (FW_ / 2 - 1)) && (col <= tx0 + TILE_ - 1 + FW_ / 2);
        if (hit) {
            const int idx = atomicAdd(&s_cnt, 1);
            // pack: part(8b) | row(9b) | col(9b)
            s_list[idx] = ((unsigned)part << 18) | ((unsigned)row << 9) | (unsigned)col;
        }
    }
    __syncthreads();
    const int cnt = s_cnt;

    // ---- Phase 2: wave w handles hits w, w+4, ... over the FULL tile ----
    // Thread (lane) owns a 4x4 px patch: rows r0..r0+3, cols c0..c0+3.
    const int w    = t >> 6;
    const int lane = t & 63;
    const int r0   = (lane >> 3) * 4;          // 0,4,...,28
    const int c0   = (lane & 7) * 4;           // 0,4,...,28
    const int yq0  = ty0 + r0 + (FH_ / 2);     // filter row i = yq0 - row (+q)
    const int xq2  = (tx0 + c0 + (FW_ / 2) + 32) * 2;  // byte col in bank row
    const char* bankb = (const char*)bank;

    // acc element (q,e) = acc2[q*2 + (e>>1)][e&1]  (q=row 0..3, e=col 0..3)
    v2f acc2[8];
#pragma unroll
    for (int s = 0; s < 8; ++s) acc2[s] = (v2f)(0.f);

    struct HitLoads { b8u w[4]; };

    auto issue = [&](unsigned v) {
        const int row        = (int)((v >> 9) & 511u);
        const unsigned col2  = (v & 511u) << 1;
        const unsigned pbase = (v >> 18) << 14;        // part * 16384 bytes
        const unsigned off0  = pbase + (unsigned)xq2 - col2;  // row-0 byte addr
        const int i0 = yq0 - row;                      // filter row for q=0
        HitLoads h;
#pragma unroll
        for (int q = 0; q < 4; ++q) {
            const int iq = i0 + q;
            unsigned off = off0 + (unsigned)iq * 256u;
            // invalid row -> part's row-0 col-pad zeros (bytes pbase..pbase+7)
            off = ((unsigned)iq < (unsigned)FH_) ? off : pbase;
            h.w[q] = *(const b8u*)(bankb + off);       // unconditional 8B
        }
        return h;
    };
    auto accum = [&](const HitLoads& h) {
#pragma unroll
        for (int q = 0; q < 4; ++q) {
            v2f lo, hi;
            lo.x = __uint_as_float(h.w[q].x << 16);
            lo.y = __uint_as_float(h.w[q].x & 0xffff0000u);
            hi.x = __uint_as_float(h.w[q].y << 16);
            hi.y = __uint_as_float(h.w[q].y & 0xffff0000u);
            acc2[q * 2 + 0] += lo;                     // v_pk_add_f32
            acc2[q * 2 + 1] += hi;
        }
    };

    int k = w;
    for (; k + 12 < cnt; k += 16) {       // 4 hits -> 16 loads in flight
        const unsigned va = s_list[k];
        const unsigned vb = s_list[k + 4];
        const unsigned vc = s_list[k + 8];
        const unsigned vd = s_list[k + 12];
        HitLoads ha = issue(va);
        HitLoads hb = issue(vb);
        HitLoads hc = issue(vc);
        HitLoads hd = issue(vd);
        accum(ha); accum(hb); accum(hc); accum(hd);
    }
    for (; k < cnt; k += 4) {             // tail, one hit at a time
        HitLoads h = issue(s_list[k]);
        accum(h);
    }

    // ---- Phase 3: combine the 4 waves' partial tiles via LDS ----
#pragma unroll
    for (int s = 0; s < 16; ++s) {
        const float a = acc2[(s >> 2) * 2 + ((s >> 1) & 1)][s & 1];
        s_red[(s * 4 + w) * 64 + lane] = a;            // lane-contiguous
    }
    __syncthreads();

    // Thread (w,lane) reduces slots s = w*4+e over all 4 waves:
    // px row = (lane>>3)*4 + w, cols = (lane&7)*4 + e  (e=0..3 consecutive)
    float sum[4];
#pragma unroll
    for (int e = 0; e < 4; ++e) {
        const int s = w * 4 + e;
        sum[e] = s_red[(s * 4 + 0) * 64 + lane] + s_red[(s * 4 + 1) * 64 + lane]
               + s_red[(s * 4 + 2) * 64 + lane] + s_red[(s * 4 + 3) * 64 + lane];
    }
    const int rr = (lane >> 3) * 4 + w;
    const int cc = (lane & 7) * 4;
    float* o = out + (ty0 + rr) * W_ + (tx0 + cc);
    atomicAdd(o + 0, sum[0]);
    atomicAdd(o + 1, sum[1]);
    atomicAdd(o + 2, sum[2]);
    atomicAdd(o + 3, sum[3]);
}

extern "C" void kernel_launch(void* const* d_in, const int* in_sizes, int n_in,
                              void* d_out, int out_size, void* d_ws, size_t ws_size,
                              hipStream_t stream) {
    const int*   phw     = (const int*)d_in[0];
    const float* filters = (const float*)d_in[1];
    float*       out     = (float*)d_out;
    unsigned int* bank   = (unsigned int*)d_ws;   // 256*64*128*2B = 4 MB
    const int n = in_sizes[0] / 3;

    pad_filters_kernel<<<NPARTS_, 256, 0, stream>>>(filters, bank, out);

    const int segs = (n + SEG_LEN_ - 1) / SEG_LEN_;   // = 4 at N=8192
    dim3 grid(W_ / TILE_, H_ / TILE_, segs);
    render_tile_kernel<<<grid, THREADS_, 0, stream>>>(
        phw, (const unsigned short*)bank, out, n);
}